// Round 21
// baseline (321.162 us; speedup 1.0000x reference)
//
#include <hip/hip_runtime.h>
#include <hip/hip_bf16.h>

using bf16 = __hip_bfloat16;
typedef __attribute__((ext_vector_type(8))) short bf16x8;
typedef __attribute__((ext_vector_type(4))) float f32x4;

#define DDIM 1024

__device__ __forceinline__ void gload16(const bf16* g, bf16* l) {
    __builtin_amdgcn_global_load_lds(
        (const __attribute__((address_space(1))) void*)g,
        (__attribute__((address_space(3))) void*)l, 16, 0, 0);
}
__device__ __forceinline__ short f2b(float f) {
    return (short)__bfloat16_as_ushort(__float2bfloat16(f));
}

// Fusion: out = lrelu((x @ Mt^T) * dco + add)
//   Mt[o,k] = sum_j (W[o,j]*w[j]) * W[j,k];  dco[o] = rsqrt(sum_j (W[o,j]*w[j])^2 + 1e-8)
//   add[o]  = (sum_j b[j]*w[j]*W[o,j])*dco[o] + nraw[o]*ns + b[o]

__global__ void prep_kernel(const float* __restrict__ W, const float* __restrict__ w,
                            const float* __restrict__ b, const float* __restrict__ nstr,
                            const float* __restrict__ nraw,
                            float* __restrict__ dco, float* __restrict__ add,
                            bf16* __restrict__ Qb) {
    int o = blockIdx.x;
    int lane = threadIdx.x;
    const float* Wrow = W + (size_t)o * DDIM;
    bf16* Qrow = Qb + (size_t)o * DDIM;
    float s = 0.f, c = 0.f;
    for (int j = lane; j < DDIM; j += 64) {
        float q = Wrow[j] * w[j];
        Qrow[j] = __float2bfloat16(q);
        s += q * q;
        c += b[j] * q;
    }
#pragma unroll
    for (int off = 32; off; off >>= 1) {
        s += __shfl_down(s, off);
        c += __shfl_down(c, off);
    }
    if (lane == 0) {
        float d = rsqrtf(s + 1e-8f);
        dco[o] = d;
        add[o] = c * d + nraw[o] * nstr[0] + b[o];
    }
}

__global__ void transpose_kernel(const float* __restrict__ W, bf16* __restrict__ Wt) {
    __shared__ bf16 tile[64][72];
    int bi = blockIdx.x * 64;
    int bj = blockIdx.y * 64;
    int r  = threadIdx.x >> 2;
    int c4 = (threadIdx.x & 3) * 16;
    const float* src = W + (size_t)(bi + r) * DDIM + bj + c4;
#pragma unroll
    for (int i = 0; i < 16; ++i) tile[r][c4 + i] = __float2bfloat16(src[i]);
    __syncthreads();
    bf16* dst = Wt + (size_t)(bj + r) * DDIM + bi + c4;
#pragma unroll
    for (int i = 0; i < 16; ++i) dst[i] = tile[c4 + i][r];
}

__global__ __launch_bounds__(256) void mgemm(const bf16* __restrict__ A,
                                             const bf16* __restrict__ B,
                                             bf16* __restrict__ C) {
    __shared__ bf16 lA[128 * 32];
    __shared__ bf16 lB[128 * 32];
    int tid  = threadIdx.x;
    int lane = tid & 63, wid = tid >> 6;
    int wr = wid >> 1, wc = wid & 1;
    int brow = blockIdx.x >> 3;
    int bcol = blockIdx.x & 7;
    const bf16* Ab = A + (size_t)brow * 128 * DDIM;
    const bf16* Bb = B + (size_t)bcol * 128 * DDIM;
    int srow = tid >> 2;
    int scol = (tid & 3) * 8;
    f32x4 acc[4][4];
#pragma unroll
    for (int m = 0; m < 4; ++m)
#pragma unroll
        for (int n = 0; n < 4; ++n) acc[m][n] = (f32x4){0.f, 0.f, 0.f, 0.f};
    int r16 = lane & 15, kh = lane >> 4;
    for (int k0 = 0; k0 < DDIM; k0 += 32) {
        gload16(Ab + (size_t)srow * DDIM + k0 + scol,        lA + tid * 8);
        gload16(Ab + (size_t)(srow + 64) * DDIM + k0 + scol, lA + (tid + 256) * 8);
        gload16(Bb + (size_t)srow * DDIM + k0 + scol,        lB + tid * 8);
        gload16(Bb + (size_t)(srow + 64) * DDIM + k0 + scol, lB + (tid + 256) * 8);
        __syncthreads();
        bf16x8 aF[4], bF[4];
#pragma unroll
        for (int m = 0; m < 4; ++m) {
            aF[m] = *(const bf16x8*)(lA + ((wr * 64 + m * 16 + r16) * 32 + kh * 8));
            bF[m] = *(const bf16x8*)(lB + ((wc * 64 + m * 16 + r16) * 32 + kh * 8));
        }
#pragma unroll
        for (int m = 0; m < 4; ++m)
#pragma unroll
            for (int n = 0; n < 4; ++n)
                acc[m][n] = __builtin_amdgcn_mfma_f32_16x16x32_bf16(aF[m], bF[n], acc[m][n], 0, 0, 0);
        __syncthreads();
    }
    int cb = lane & 15;
    int rb = (lane >> 4) * 4;
#pragma unroll
    for (int n = 0; n < 4; ++n) {
        int col = bcol * 128 + wc * 64 + n * 16 + cb;
#pragma unroll
        for (int m = 0; m < 4; ++m)
#pragma unroll
            for (int j = 0; j < 4; ++j) {
                int row = wr * 64 + m * 16 + rb + j;
                C[((size_t)brow * 128 + row) * DDIM + col] = __float2bfloat16(acc[m][n][j]);
            }
    }
}

// ---- big GEMM: out[n][o] = lrelu(dco[o]*sum_j x[n,j]*Mt[o,j] + add[o]) ----
// R20 with ONE change: the 24 fragment ds_reads are issued at the VERY TOP of the
// tile (before the A-landing VMWs and WRITE_A). Reads hit buf b, writes hit nb (no
// hazard); ds_writes queue behind reads with an end-of-tile LGW+BAR deadline. The
// LDS read stream (longest shared-pipe stream) starts ~2 waits + 4 writes earlier.
#define BAR()  __builtin_amdgcn_s_barrier()
#define VMW(n) asm volatile("s_waitcnt vmcnt(" #n ")")
#define LGW()  asm volatile("s_waitcnt lgkmcnt(0)")

__global__ __launch_bounds__(512, 2) void big_gemm(
    const float* __restrict__ Af, const bf16* __restrict__ Bw,
    const float* __restrict__ dco, const float* __restrict__ add,
    float* __restrict__ Cf)
{
    __shared__ bf16 sA[2][2][256 * 32];   // 64 KiB
    __shared__ bf16 sB[2][2][256 * 32];   // 64 KiB

    const int tid  = threadIdx.x;
    const int lane = tid & 63;
    const int wid  = tid >> 6;
    const int wr   = wid >> 2, wc = wid & 3;      // 2 x 4 waves, each 128x64
    const int r16  = lane & 15, kh = lane >> 4;
    const int fso  = (kh ^ ((r16 >> 1) & 3)) * 8; // swizzled frag slot (elems)

    int bx  = blockIdx.x;                          // 1024 blocks
    int swz = (bx & 7) * 128 + (bx >> 3);          // bijective XCD swizzle
    int brow = swz >> 2, bcol = swz & 3;

    const float* Asrc_f = Af + (size_t)(brow * 256) * DDIM;
    const bf16*  Bsrc   = Bw + (size_t)(bcol * 256) * DDIM;

    const int sr  = tid >> 2;                      // staging row 0..127 (and +128)
    const int ssl = (tid & 3) ^ ((sr >> 1) & 3);   // swizzled 16B source slot

    f32x4 acc[8][4];
#pragma unroll
    for (int m = 0; m < 8; ++m)
#pragma unroll
        for (int n = 0; n < 4; ++n) acc[m][n] = (f32x4){0.f, 0.f, 0.f, 0.f};

    bf16x8 aF[4], aF2[4], bF[4];    // ks0 fragments
    bf16x8 cF[4], cF2[4], dF[4];    // ks1 fragments
    float4 gA0, gA1, gA2, gA3;      // A-prefetch regs (K-half 0 group)
    float4 gB0, gB1, gB2, gB3;      // A-prefetch regs (K-half 1 group)

#define STAGE_B(buf, kt, ks) do { \
    const bf16* _s = Bsrc + (size_t)sr * DDIM + ((kt) * 64 + (ks) * 32 + ssl * 8); \
    gload16(_s,               &sB[buf][ks][tid * 8]); \
    gload16(_s + 128 * DDIM,  &sB[buf][ks][(tid + 512) * 8]); \
} while (0)

#define LOAD_A_F(g0, g1, g2, g3, kt, ks) do { \
    const float* _p = Asrc_f + (size_t)sr * DDIM + ((kt) * 64 + (ks) * 32 + (tid & 3) * 8); \
    g0 = ((const float4*)_p)[0]; g1 = ((const float4*)_p)[1]; \
    const float* _q = _p + 128 * DDIM; \
    g2 = ((const float4*)_q)[0]; g3 = ((const float4*)_q)[1]; \
} while (0)

#define WRITE_A(buf, ks, g0, g1, g2, g3) do { \
    bf16x8 _pk; \
    _pk[0]=f2b(g0.x); _pk[1]=f2b(g0.y); _pk[2]=f2b(g0.z); _pk[3]=f2b(g0.w); \
    _pk[4]=f2b(g1.x); _pk[5]=f2b(g1.y); _pk[6]=f2b(g1.z); _pk[7]=f2b(g1.w); \
    *(bf16x8*)&sA[buf][ks][sr * 32 + ssl * 8] = _pk; \
    _pk[0]=f2b(g2.x); _pk[1]=f2b(g2.y); _pk[2]=f2b(g2.z); _pk[3]=f2b(g2.w); \
    _pk[4]=f2b(g3.x); _pk[5]=f2b(g3.y); _pk[6]=f2b(g3.z); _pk[7]=f2b(g3.w); \
    *(bf16x8*)&sA[buf][ks][(sr + 128) * 32 + ssl * 8] = _pk; \
} while (0)

#define RD_A(dst, buf, ks, mh) do { \
    _Pragma("unroll") for (int _m = 0; _m < 4; ++_m) \
        dst[_m] = *(const bf16x8*)&sA[buf][ks][(wr * 128 + (mh) * 64 + _m * 16 + r16) * 32 + fso]; \
} while (0)

#define RD_B(dst, buf, ks) do { \
    _Pragma("unroll") for (int _n = 0; _n < 4; ++_n) \
        dst[_n] = *(const bf16x8*)&sB[buf][ks][(wc * 64 + _n * 16 + r16) * 32 + fso]; \
} while (0)

// 32 MFMA: both mh halves x 4 n for one ks
#define MFMA32(A0, A1, B) do { \
    __builtin_amdgcn_s_setprio(1); \
    _Pragma("unroll") for (int _m = 0; _m < 4; ++_m) { \
        acc[_m][0] = __builtin_amdgcn_mfma_f32_16x16x32_bf16(A0[_m], B[0], acc[_m][0], 0, 0, 0); \
        acc[_m][1] = __builtin_amdgcn_mfma_f32_16x16x32_bf16(A0[_m], B[1], acc[_m][1], 0, 0, 0); \
        acc[_m][2] = __builtin_amdgcn_mfma_f32_16x16x32_bf16(A0[_m], B[2], acc[_m][2], 0, 0, 0); \
        acc[_m][3] = __builtin_amdgcn_mfma_f32_16x16x32_bf16(A0[_m], B[3], acc[_m][3], 0, 0, 0); \
    } \
    _Pragma("unroll") for (int _m = 0; _m < 4; ++_m) { \
        acc[4+_m][0] = __builtin_amdgcn_mfma_f32_16x16x32_bf16(A1[_m], B[0], acc[4+_m][0], 0, 0, 0); \
        acc[4+_m][1] = __builtin_amdgcn_mfma_f32_16x16x32_bf16(A1[_m], B[1], acc[4+_m][1], 0, 0, 0); \
        acc[4+_m][2] = __builtin_amdgcn_mfma_f32_16x16x32_bf16(A1[_m], B[2], acc[4+_m][2], 0, 0, 0); \
        acc[4+_m][3] = __builtin_amdgcn_mfma_f32_16x16x32_bf16(A1[_m], B[3], acc[4+_m][3], 0, 0, 0); \
    } \
    __builtin_amdgcn_s_setprio(0); \
} while (0)

    // ---- prologue; vmcnt FIFO ledger in comments ----
    LOAD_A_F(gA0, gA1, gA2, gA3, 0, 0);   // [A0K0:4]
    LOAD_A_F(gB0, gB1, gB2, gB3, 0, 1);   // [A0:8]
    VMW(4);                               // A0K0 landed
    WRITE_A(0, 0, gA0, gA1, gA2, gA3);
    VMW(0);                               // A0K1 landed
    WRITE_A(0, 1, gB0, gB1, gB2, gB3);
    STAGE_B(0, 0, 0); STAGE_B(0, 0, 1);   // [SB0:4]
    LOAD_A_F(gA0, gA1, gA2, gA3, 1, 0);   // [SB0:4, A1K0:4]
    LOAD_A_F(gB0, gB1, gB2, gB3, 1, 1);   // [SB0:4, A1:8]
    LGW();                                // A0 ds_writes visible
    VMW(8);                               // SB0 retired -> B0 in LDS
    BAR();
    // entry invariant (tile t): buf b holds A(t),B(t); FIFO = [A(t+1):8]

    for (int t = 0; t < 16; ++t) {
        int b = t & 1, nb = b ^ 1;
        int t1 = t + 1; if (t1 > 15) t1 = 15;   // tail clamp (never read)
        int t2 = t + 2; if (t2 > 15) t2 = 15;

        // --- FRONT-LOADED: stage B(t+1) + issue all 24 frag reads first ---
        STAGE_B(nb, t1, 0); STAGE_B(nb, t1, 1);   // [A(t+1):8, SB(t+1):4]
        RD_A(aF,  b, 0, 0); RD_A(aF2, b, 0, 1); RD_B(bF, b, 0);
        RD_A(cF,  b, 1, 0); RD_A(cF2, b, 1, 1); RD_B(dF, b, 1);

        // --- A-staging: waits on loads issued mid-tile t-1 (covered) ---
        VMW(8);                           // A(t+1)K0 landed; [A(t+1)K1:4, SB:4]
        WRITE_A(nb, 0, gA0, gA1, gA2, gA3);
        VMW(4);                           // A(t+1)K1 landed; [SB:4]
        WRITE_A(nb, 1, gB0, gB1, gB2, gB3);

        MFMA32(aF, aF2, bF);    // ks0 — frag reads had maximal service lead time

        // --- A(t+2) loads between bursts (R20 placement) ---
        LOAD_A_F(gA0, gA1, gA2, gA3, t2, 0);      // +4
        LOAD_A_F(gB0, gB1, gB2, gB3, t2, 1);      // +4 -> [SB:4, A(t+2):8]

        MFMA32(cF, cF2, dF);    // ks1

        VMW(8);                 // SB(t+1) retired -> B(t+1) in LDS; [A(t+2):8]
        LGW();                  // frag reads consumed + A(t+1) ds_writes visible
        BAR();
        // exit invariant: [A(t+2):8] ✓
    }

    // ---- fused epilogue ----
    int crb = brow * 256 + wr * 128 + kh * 4;
    int ccb = bcol * 256 + wc * 64 + r16;
#pragma unroll
    for (int n = 0; n < 4; ++n) {
        int col = ccb + n * 16;
        float cm = dco[col], ca = add[col];
#pragma unroll
        for (int m = 0; m < 8; ++m) {
#pragma unroll
            for (int j = 0; j < 4; ++j) {
                size_t idx = (size_t)(crb + m * 16 + j) * DDIM + col;
                float v = acc[m][n][j] * cm + ca;
                v = (v >= 0.f) ? v : 0.01f * v;
                Cf[idx] = v;
            }
        }
    }
#undef STAGE_B
#undef LOAD_A_F
#undef WRITE_A
#undef RD_A
#undef RD_B
#undef MFMA32
}

extern "C" void kernel_launch(void* const* d_in, const int* in_sizes, int n_in,
                              void* d_out, int out_size, void* d_ws, size_t ws_size,
                              hipStream_t stream) {
    const float* x  = (const float*)d_in[0];
    const float* w  = (const float*)d_in[1];
    const float* W  = (const float*)d_in[2];
    const float* b  = (const float*)d_in[3];
    const float* ns = (const float*)d_in[4];
    const float* nr = (const float*)d_in[5];
    float* out = (float*)d_out;

    float* dco = (float*)d_ws;                                   // 4 KB
    float* add = dco + DDIM;                                     // 4 KB
    bf16*  Qb  = (bf16*)((char*)d_ws + 8192);                    // 2 MB
    bf16*  Wt  = (bf16*)((char*)d_ws + 8192 + 2097152);          // 2 MB
    bf16*  Mt  = (bf16*)((char*)d_ws + 8192 + 2 * 2097152);      // 2 MB

    int M = in_sizes[0] / DDIM;                                  // 65536
    int grid = (M / 256) * (DDIM / 256);                         // 1024

    prep_kernel<<<DDIM, 64, 0, stream>>>(W, w, b, ns, nr, dco, add, Qb);
    transpose_kernel<<<dim3(16, 16), 256, 0, stream>>>(W, Wt);
    mgemm<<<64, 256, 0, stream>>>(Qb, Wt, Mt);
    big_gemm<<<grid, 512, 0, stream>>>(x, Mt, dco, add, out);
}

// Round 22
// 241.035 us; speedup vs baseline: 1.3324x; 1.3324x over previous
//
#include <hip/hip_runtime.h>
#include <hip/hip_bf16.h>

using bf16 = __hip_bfloat16;
typedef __attribute__((ext_vector_type(8))) short bf16x8;
typedef __attribute__((ext_vector_type(4))) float f32x4;

#define DDIM 1024

__device__ __forceinline__ void gload16(const bf16* g, bf16* l) {
    __builtin_amdgcn_global_load_lds(
        (const __attribute__((address_space(1))) void*)g,
        (__attribute__((address_space(3))) void*)l, 16, 0, 0);
}
__device__ __forceinline__ short f2b(float f) {
    return (short)__bfloat16_as_ushort(__float2bfloat16(f));
}

// Fusion: out = lrelu((x @ Mt^T) * dco + add)
//   Mt[o,k] = sum_j (W[o,j]*w[j]) * W[j,k];  dco[o] = rsqrt(sum_j (W[o,j]*w[j])^2 + 1e-8)
//   add[o]  = (sum_j b[j]*w[j]*W[o,j])*dco[o] + nraw[o]*ns + b[o]

__global__ void prep_kernel(const float* __restrict__ W, const float* __restrict__ w,
                            const float* __restrict__ b, const float* __restrict__ nstr,
                            const float* __restrict__ nraw,
                            float* __restrict__ dco, float* __restrict__ add,
                            bf16* __restrict__ Qb) {
    int o = blockIdx.x;
    int lane = threadIdx.x;
    const float* Wrow = W + (size_t)o * DDIM;
    bf16* Qrow = Qb + (size_t)o * DDIM;
    float s = 0.f, c = 0.f;
    for (int j = lane; j < DDIM; j += 64) {
        float q = Wrow[j] * w[j];
        Qrow[j] = __float2bfloat16(q);
        s += q * q;
        c += b[j] * q;
    }
#pragma unroll
    for (int off = 32; off; off >>= 1) {
        s += __shfl_down(s, off);
        c += __shfl_down(c, off);
    }
    if (lane == 0) {
        float d = rsqrtf(s + 1e-8f);
        dco[o] = d;
        add[o] = c * d + nraw[o] * nstr[0] + b[o];
    }
}

__global__ void transpose_kernel(const float* __restrict__ W, bf16* __restrict__ Wt) {
    __shared__ bf16 tile[64][72];
    int bi = blockIdx.x * 64;
    int bj = blockIdx.y * 64;
    int r  = threadIdx.x >> 2;
    int c4 = (threadIdx.x & 3) * 16;
    const float* src = W + (size_t)(bi + r) * DDIM + bj + c4;
#pragma unroll
    for (int i = 0; i < 16; ++i) tile[r][c4 + i] = __float2bfloat16(src[i]);
    __syncthreads();
    bf16* dst = Wt + (size_t)(bj + r) * DDIM + bi + c4;
#pragma unroll
    for (int i = 0; i < 16; ++i) dst[i] = tile[c4 + i][r];
}

__global__ __launch_bounds__(256) void mgemm(const bf16* __restrict__ A,
                                             const bf16* __restrict__ B,
                                             bf16* __restrict__ C) {
    __shared__ bf16 lA[128 * 32];
    __shared__ bf16 lB[128 * 32];
    int tid  = threadIdx.x;
    int lane = tid & 63, wid = tid >> 6;
    int wr = wid >> 1, wc = wid & 1;
    int brow = blockIdx.x >> 3;
    int bcol = blockIdx.x & 7;
    const bf16* Ab = A + (size_t)brow * 128 * DDIM;
    const bf16* Bb = B + (size_t)bcol * 128 * DDIM;
    int srow = tid >> 2;
    int scol = (tid & 3) * 8;
    f32x4 acc[4][4];
#pragma unroll
    for (int m = 0; m < 4; ++m)
#pragma unroll
        for (int n = 0; n < 4; ++n) acc[m][n] = (f32x4){0.f, 0.f, 0.f, 0.f};
    int r16 = lane & 15, kh = lane >> 4;
    for (int k0 = 0; k0 < DDIM; k0 += 32) {
        gload16(Ab + (size_t)srow * DDIM + k0 + scol,        lA + tid * 8);
        gload16(Ab + (size_t)(srow + 64) * DDIM + k0 + scol, lA + (tid + 256) * 8);
        gload16(Bb + (size_t)srow * DDIM + k0 + scol,        lB + tid * 8);
        gload16(Bb + (size_t)(srow + 64) * DDIM + k0 + scol, lB + (tid + 256) * 8);
        __syncthreads();
        bf16x8 aF[4], bF[4];
#pragma unroll
        for (int m = 0; m < 4; ++m) {
            aF[m] = *(const bf16x8*)(lA + ((wr * 64 + m * 16 + r16) * 32 + kh * 8));
            bF[m] = *(const bf16x8*)(lB + ((wc * 64 + m * 16 + r16) * 32 + kh * 8));
        }
#pragma unroll
        for (int m = 0; m < 4; ++m)
#pragma unroll
            for (int n = 0; n < 4; ++n)
                acc[m][n] = __builtin_amdgcn_mfma_f32_16x16x32_bf16(aF[m], bF[n], acc[m][n], 0, 0, 0);
        __syncthreads();
    }
    int cb = lane & 15;
    int rb = (lane >> 4) * 4;
#pragma unroll
    for (int n = 0; n < 4; ++n) {
        int col = bcol * 128 + wc * 64 + n * 16 + cb;
#pragma unroll
        for (int m = 0; m < 4; ++m)
#pragma unroll
            for (int j = 0; j < 4; ++j) {
                int row = wr * 64 + m * 16 + rb + j;
                C[((size_t)brow * 128 + row) * DDIM + col] = __float2bfloat16(acc[m][n][j]);
            }
    }
}

// ---- big GEMM: out[n][o] = lrelu(dco[o]*sum_j x[n,j]*Mt[o,j] + add[o]) ----
// R20 final: one barrier per K-tile; 24 frag ds_reads after the (covered) A-landing
// waits; A(t+2) global loads issued BETWEEN the two MFMA bursts so the next tile's
// top-of-tile VMWs wait on ~1500-cycle-old loads. No register spill (VGPR 120).
#define BAR()  __builtin_amdgcn_s_barrier()
#define VMW(n) asm volatile("s_waitcnt vmcnt(" #n ")")
#define LGW()  asm volatile("s_waitcnt lgkmcnt(0)")

__global__ __launch_bounds__(512, 2) void big_gemm(
    const float* __restrict__ Af, const bf16* __restrict__ Bw,
    const float* __restrict__ dco, const float* __restrict__ add,
    float* __restrict__ Cf)
{
    __shared__ bf16 sA[2][2][256 * 32];   // 64 KiB
    __shared__ bf16 sB[2][2][256 * 32];   // 64 KiB

    const int tid  = threadIdx.x;
    const int lane = tid & 63;
    const int wid  = tid >> 6;
    const int wr   = wid >> 2, wc = wid & 3;      // 2 x 4 waves, each 128x64
    const int r16  = lane & 15, kh = lane >> 4;
    const int fso  = (kh ^ ((r16 >> 1) & 3)) * 8; // swizzled frag slot (elems)

    int bx  = blockIdx.x;                          // 1024 blocks
    int swz = (bx & 7) * 128 + (bx >> 3);          // bijective XCD swizzle
    int brow = swz >> 2, bcol = swz & 3;

    const float* Asrc_f = Af + (size_t)(brow * 256) * DDIM;
    const bf16*  Bsrc   = Bw + (size_t)(bcol * 256) * DDIM;

    const int sr  = tid >> 2;                      // staging row 0..127 (and +128)
    const int ssl = (tid & 3) ^ ((sr >> 1) & 3);   // swizzled 16B source slot

    f32x4 acc[8][4];
#pragma unroll
    for (int m = 0; m < 8; ++m)
#pragma unroll
        for (int n = 0; n < 4; ++n) acc[m][n] = (f32x4){0.f, 0.f, 0.f, 0.f};

    bf16x8 aF[4], aF2[4], bF[4];    // ks0 fragments
    bf16x8 cF[4], cF2[4], dF[4];    // ks1 fragments
    float4 gA0, gA1, gA2, gA3;      // A-prefetch regs (K-half 0 group)
    float4 gB0, gB1, gB2, gB3;      // A-prefetch regs (K-half 1 group)

#define STAGE_B(buf, kt, ks) do { \
    const bf16* _s = Bsrc + (size_t)sr * DDIM + ((kt) * 64 + (ks) * 32 + ssl * 8); \
    gload16(_s,               &sB[buf][ks][tid * 8]); \
    gload16(_s + 128 * DDIM,  &sB[buf][ks][(tid + 512) * 8]); \
} while (0)

#define LOAD_A_F(g0, g1, g2, g3, kt, ks) do { \
    const float* _p = Asrc_f + (size_t)sr * DDIM + ((kt) * 64 + (ks) * 32 + (tid & 3) * 8); \
    g0 = ((const float4*)_p)[0]; g1 = ((const float4*)_p)[1]; \
    const float* _q = _p + 128 * DDIM; \
    g2 = ((const float4*)_q)[0]; g3 = ((const float4*)_q)[1]; \
} while (0)

#define WRITE_A(buf, ks, g0, g1, g2, g3) do { \
    bf16x8 _pk; \
    _pk[0]=f2b(g0.x); _pk[1]=f2b(g0.y); _pk[2]=f2b(g0.z); _pk[3]=f2b(g0.w); \
    _pk[4]=f2b(g1.x); _pk[5]=f2b(g1.y); _pk[6]=f2b(g1.z); _pk[7]=f2b(g1.w); \
    *(bf16x8*)&sA[buf][ks][sr * 32 + ssl * 8] = _pk; \
    _pk[0]=f2b(g2.x); _pk[1]=f2b(g2.y); _pk[2]=f2b(g2.z); _pk[3]=f2b(g2.w); \
    _pk[4]=f2b(g3.x); _pk[5]=f2b(g3.y); _pk[6]=f2b(g3.z); _pk[7]=f2b(g3.w); \
    *(bf16x8*)&sA[buf][ks][(sr + 128) * 32 + ssl * 8] = _pk; \
} while (0)

#define RD_A(dst, buf, ks, mh) do { \
    _Pragma("unroll") for (int _m = 0; _m < 4; ++_m) \
        dst[_m] = *(const bf16x8*)&sA[buf][ks][(wr * 128 + (mh) * 64 + _m * 16 + r16) * 32 + fso]; \
} while (0)

#define RD_B(dst, buf, ks) do { \
    _Pragma("unroll") for (int _n = 0; _n < 4; ++_n) \
        dst[_n] = *(const bf16x8*)&sB[buf][ks][(wc * 64 + _n * 16 + r16) * 32 + fso]; \
} while (0)

// 32 MFMA: both mh halves x 4 n for one ks
#define MFMA32(A0, A1, B) do { \
    __builtin_amdgcn_s_setprio(1); \
    _Pragma("unroll") for (int _m = 0; _m < 4; ++_m) { \
        acc[_m][0] = __builtin_amdgcn_mfma_f32_16x16x32_bf16(A0[_m], B[0], acc[_m][0], 0, 0, 0); \
        acc[_m][1] = __builtin_amdgcn_mfma_f32_16x16x32_bf16(A0[_m], B[1], acc[_m][1], 0, 0, 0); \
        acc[_m][2] = __builtin_amdgcn_mfma_f32_16x16x32_bf16(A0[_m], B[2], acc[_m][2], 0, 0, 0); \
        acc[_m][3] = __builtin_amdgcn_mfma_f32_16x16x32_bf16(A0[_m], B[3], acc[_m][3], 0, 0, 0); \
    } \
    _Pragma("unroll") for (int _m = 0; _m < 4; ++_m) { \
        acc[4+_m][0] = __builtin_amdgcn_mfma_f32_16x16x32_bf16(A1[_m], B[0], acc[4+_m][0], 0, 0, 0); \
        acc[4+_m][1] = __builtin_amdgcn_mfma_f32_16x16x32_bf16(A1[_m], B[1], acc[4+_m][1], 0, 0, 0); \
        acc[4+_m][2] = __builtin_amdgcn_mfma_f32_16x16x32_bf16(A1[_m], B[2], acc[4+_m][2], 0, 0, 0); \
        acc[4+_m][3] = __builtin_amdgcn_mfma_f32_16x16x32_bf16(A1[_m], B[3], acc[4+_m][3], 0, 0, 0); \
    } \
    __builtin_amdgcn_s_setprio(0); \
} while (0)

    // ---- prologue; vmcnt FIFO ledger in comments ----
    LOAD_A_F(gA0, gA1, gA2, gA3, 0, 0);   // [A0K0:4]
    LOAD_A_F(gB0, gB1, gB2, gB3, 0, 1);   // [A0:8]
    VMW(4);                               // A0K0 landed
    WRITE_A(0, 0, gA0, gA1, gA2, gA3);
    VMW(0);                               // A0K1 landed
    WRITE_A(0, 1, gB0, gB1, gB2, gB3);
    STAGE_B(0, 0, 0); STAGE_B(0, 0, 1);   // [SB0:4]
    LOAD_A_F(gA0, gA1, gA2, gA3, 1, 0);   // [SB0:4, A1K0:4]
    LOAD_A_F(gB0, gB1, gB2, gB3, 1, 1);   // [SB0:4, A1:8]
    LGW();                                // A0 ds_writes visible
    VMW(8);                               // SB0 retired -> B0 in LDS
    BAR();
    // entry invariant (tile t): buf b holds A(t),B(t); FIFO = [A(t+1):8]

    for (int t = 0; t < 16; ++t) {
        int b = t & 1, nb = b ^ 1;
        int t1 = t + 1; if (t1 > 15) t1 = 15;   // tail clamp (never read)
        int t2 = t + 2; if (t2 > 15) t2 = 15;

        // --- A-staging at TOP: A(t+1) was issued mid-tile t-1 (~1500 cyc ago) ---
        VMW(4);                           // A(t+1)K0 landed (covered); [A(t+1)K1:4]
        WRITE_A(nb, 0, gA0, gA1, gA2, gA3);
        VMW(0);                           // A(t+1)K1 landed (covered); []
        WRITE_A(nb, 1, gB0, gB1, gB2, gB3);
        STAGE_B(nb, t1, 0); STAGE_B(nb, t1, 1);   // [SB(t+1):4]

        // all 24 fragment reads upfront — LDS services them under the ks0 burst
        RD_A(aF,  b, 0, 0); RD_A(aF2, b, 0, 1); RD_B(bF, b, 0);
        RD_A(cF,  b, 1, 0); RD_A(cF2, b, 1, 1); RD_B(dF, b, 1);

        MFMA32(aF, aF2, bF);    // ks0 — aF/aF2/bF die here (64 VGPR freed)

        // --- A(t+2) loads BETWEEN bursts: latency hides under ks1 + next-tile top ---
        LOAD_A_F(gA0, gA1, gA2, gA3, t2, 0);      // +4
        LOAD_A_F(gB0, gB1, gB2, gB3, t2, 1);      // +4 -> [SB:4, A(t+2):8]

        MFMA32(cF, cF2, dF);    // ks1

        VMW(8);                 // SB(t+1) retired -> B(t+1) in LDS; [A(t+2):8]
        LGW();                  // frag reads consumed + A(t+1) ds_writes visible
        BAR();
        // exit invariant: [A(t+2):8] ✓
    }

    // ---- fused epilogue ----
    int crb = brow * 256 + wr * 128 + kh * 4;
    int ccb = bcol * 256 + wc * 64 + r16;
#pragma unroll
    for (int n = 0; n < 4; ++n) {
        int col = ccb + n * 16;
        float cm = dco[col], ca = add[col];
#pragma unroll
        for (int m = 0; m < 8; ++m) {
#pragma unroll
            for (int j = 0; j < 4; ++j) {
                size_t idx = (size_t)(crb + m * 16 + j) * DDIM + col;
                float v = acc[m][n][j] * cm + ca;
                v = (v >= 0.f) ? v : 0.01f * v;
                Cf[idx] = v;
            }
        }
    }
#undef STAGE_B
#undef LOAD_A_F
#undef WRITE_A
#undef RD_A
#undef RD_B
#undef MFMA32
}

extern "C" void kernel_launch(void* const* d_in, const int* in_sizes, int n_in,
                              void* d_out, int out_size, void* d_ws, size_t ws_size,
                              hipStream_t stream) {
    const float* x  = (const float*)d_in[0];
    const float* w  = (const float*)d_in[1];
    const float* W  = (const float*)d_in[2];
    const float* b  = (const float*)d_in[3];
    const float* ns = (const float*)d_in[4];
    const float* nr = (const float*)d_in[5];
    float* out = (float*)d_out;

    float* dco = (float*)d_ws;                                   // 4 KB
    float* add = dco + DDIM;                                     // 4 KB
    bf16*  Qb  = (bf16*)((char*)d_ws + 8192);                    // 2 MB
    bf16*  Wt  = (bf16*)((char*)d_ws + 8192 + 2097152);          // 2 MB
    bf16*  Mt  = (bf16*)((char*)d_ws + 8192 + 2 * 2097152);      // 2 MB

    int M = in_sizes[0] / DDIM;                                  // 65536
    int grid = (M / 256) * (DDIM / 256);                         // 1024

    prep_kernel<<<DDIM, 64, 0, stream>>>(W, w, b, ns, nr, dco, add, Qb);
    transpose_kernel<<<dim3(16, 16), 256, 0, stream>>>(W, Wt);
    mgemm<<<64, 256, 0, stream>>>(Qb, Wt, Mt);
    big_gemm<<<grid, 512, 0, stream>>>(x, Mt, dco, add, out);
}